// Round 3
// baseline (354.324 us; speedup 1.0000x reference)
//
#include <hip/hip_runtime.h>
#include <hip/hip_bf16.h>

// ---------------------------------------------------------------------------
// RWKV TimeMix:  k = x Wk^T ; r = x Wr^T ; v = r ; y = wkv(w,u,k,v)
//                out = (sigmoid(r) * y) Wo^T
// B=16, T=1024, C=1024.  All inputs and the output are FLOAT32.
//
// Pipeline: cast x/Wk/Wr/Wo to bf16; fused kr-GEMM (N=2048, Wk|Wr split) and
// final GEMM via a 256x256 8-wave MFMA kernel with PIPELINED FRAGMENTS:
// every phase's ds_reads are issued one phase ahead and drained with COUNTED
// lgkmcnt (never 0 mid-loop), so LDS read latency/throughput hides under the
// previous MFMA cluster.  WKV scan chunk-parallel over T (16 chunks of 64),
// two passes (aggregate, fold+emit).
//
// Memory plan:
//   ws:    [xb 32 MiB][Wkb 2][Wrb 2][Wob 2]  (38 MiB; sy reuses xb slot;
//          scan aggregates reuse Wkb/Wrb slots — dead after kr-GEMM)
//   d_out: 64 MiB fp32 — mid-pipeline holds kr bf16 [M, 2C]; finally
//          overwritten with fp32 out (gemm3 reads sy from ws).
// ---------------------------------------------------------------------------

typedef __attribute__((ext_vector_type(8))) short bf16x8;   // 8 bf16 = 4 VGPRs
typedef __attribute__((ext_vector_type(4))) float f32x4;    // MFMA C/D
typedef unsigned short u16;

#define GK   1024          // K of both GEMMs (= C)
#define NKT  16            // GK / 64 K-tiles
#define ROWB 2048l         // bytes per B^T/A row = GK * 2

#define NCH  16384         // B * C channels
#define NC   16            // scan chunks over T
#define CL   64            // chunk length (T / NC)

__device__ __forceinline__ void async_copy16(const void* g, void* l) {
    __builtin_amdgcn_global_load_lds(
        (const __attribute__((address_space(1))) void*)g,
        (__attribute__((address_space(3))) void*)l,
        16 /*bytes*/, 0 /*offset*/, 0 /*aux*/);
}

// ---- fp32 -> bf16 cast, 4 elements/thread ---------------------------------
__global__ __launch_bounds__(256) void cast_f32_bf16_kernel(
    const float* __restrict__ src, __hip_bfloat16* __restrict__ dst, int n)
{
    const int i = (blockIdx.x * 256 + threadIdx.x) * 4;
    if (i + 3 < n) {
        const f32x4 v = *(const f32x4*)(src + i);
        __hip_bfloat16 o[4];
        o[0] = __float2bfloat16(v[0]);
        o[1] = __float2bfloat16(v[1]);
        o[2] = __float2bfloat16(v[2]);
        o[3] = __float2bfloat16(v[3]);
        *(__attribute__((ext_vector_type(4))) short*)(dst + i) =
            *(__attribute__((ext_vector_type(4))) short*)o;
    }
}

// ---------------------------------------------------------------------------
// 256x256 tile, BK=64, 8 waves (2M x 4N), 512 threads, 128 KiB LDS dbuf.
// C[m, bn+n] = sum_k A[m,k] * Bt[n,k];  Bt source = B0 for n < nsplit else B1.
//
// Phases repartitioned by K-half (halves live B-frags -> reg budget for the
// fragment pipeline):   P0:(m0-3,k0) P1:(m4-7,k0) P2:(m0-3,k1) P3:(m4-7,k1)
//
// Read/issue schedule (reads always ONE PHASE AHEAD of their MFMA use):
//   prologue: stage t0 A+B, vmcnt(0), stage t1 B, barrier, read {aq@k0,bq0}
//   P0: read ar@k0 (4)            | stage A(t+1)h0 | bar | lgkm(4) | MFMA
//   P1: read aq@k1 + bq1 (8)      | stage A(t+1)h1 | bar | lgkm(8) | MFMA
//   P2: read ar@k1 (4)            | bar | lgkm(4) | stage B(t+2)h0 | MFMA
//   P3: stage B(t+2)h1 | vmcnt(4) | read next {aq@k0,bq0} (8) | bar |
//       lgkm(8) | MFMA
// Counted-wait ledger: every wait sees 12 outstanding DS ops and drains only
// the group issued a full phase earlier.  vmcnt(4) at P3 proves A(t+1) and
// B(t+1) landed before the next-tile frag reads.  All reads of a B/A region
// drain (per the lgkm ledger) before the stage that overwrites it issues.
// LDS swizzle: phys_col = log_col ^ ((row & 7) << 4) (linear LDS dest,
// inverse-swizzled global source, XOR on the ds_read side).
// ---------------------------------------------------------------------------

#define MFMA16(I0, AFR, BFR) do {                                             \
    _Pragma("unroll")                                                         \
    for (int i = 0; i < 4; ++i)                                               \
        _Pragma("unroll")                                                     \
        for (int n = 0; n < 4; ++n)                                           \
            acc[(I0) + i][n] = __builtin_amdgcn_mfma_f32_16x16x32_bf16(       \
                AFR[i], BFR[n], acc[(I0) + i][n], 0, 0, 0);                   \
} while (0)

template <typename OutT>
__global__ __launch_bounds__(512, 2) void gemm256_kernel(
    const __hip_bfloat16* __restrict__ A,
    const __hip_bfloat16* __restrict__ B0,
    const __hip_bfloat16* __restrict__ B1,
    OutT* __restrict__ C,
    int ldc, int nsplit, int ntn)
{
    __shared__ __align__(16) char lds[131072];

    const int tid = threadIdx.x;

    // XCD-aware bijective swizzle (gridDim.x % 8 == 0 for both launches)
    const int nwg = gridDim.x;
    const int cpx = nwg >> 3;
    const int wg  = blockIdx.x;
    const int swz = (wg & 7) * cpx + (wg >> 3);
    const int bm  = (swz / ntn) * 256;
    const int bn  = (swz % ntn) * 256;

    const __hip_bfloat16* Bsrc;
    int bnl;
    if (bn < nsplit) { Bsrc = B0; bnl = bn; }
    else             { Bsrc = B1; bnl = bn - nsplit; }

    const int lane = tid & 63;
    const int wave = tid >> 6;
    const int nl   = lane & 15;
    const int quad = lane >> 4;
    const int wm   = (wave >> 2) * 128;   // 2 m-waves
    const int wn   = (wave & 3) * 64;     // 4 n-waves

    // ---- staging addresses: linear LDS dest, inverse-swizzled global src --
    const int r0 = tid >> 3;                          // row in half-tile 0..63
    const int cs = ((tid & 7) ^ (r0 & 7)) << 4;       // swizzled col byte
    const int od = tid * 16;                          // linear dest (o1=+8192)
    const char* Ag = (const char*)A    + (size_t)(bm  + r0) * ROWB + cs;
    const char* Bg = (const char*)Bsrc + (size_t)(bnl + r0) * ROWB + cs;

    char* ldsA0 = lds;
    char* ldsB0 = lds + 32768;
    char* ldsA1 = lds + 65536;
    char* ldsB1 = lds + 98304;

    auto stageA = [&](int kt, int h, char* dstA) {
        const char* g = Ag + (size_t)h * 128 * ROWB + (size_t)kt * 128;
        async_copy16(g,             dstA + h * 16384 + od);
        async_copy16(g + 64 * ROWB, dstA + h * 16384 + od + 8192);
    };
    auto stageB = [&](int kt, int h, char* dstB) {
        const char* g = Bg + (size_t)h * 128 * ROWB + (size_t)kt * 128;
        async_copy16(g,             dstB + h * 16384 + od);
        async_copy16(g + 64 * ROWB, dstB + h * 16384 + od + 8192);
    };

    // ---- fragment read offsets (swizzled) ---------------------------------
    const int rw   = nl & 7;
    const int ck0  = (quad ^ rw) << 4;         // k 0..31: byte col in 128B row
    const int ck1  = ((4 + quad) ^ rw) << 4;   // k 32..63
    const int arow = (wm + nl) * 128;          // byte row offset in A tile
    const int brow = (wn + nl) * 128;          // byte row offset in B tile

    f32x4 acc[8][4] = {};
    bf16x8 aq[4], ar[4], bq0[4], bq1[4];

    // ---- prologue ---------------------------------------------------------
    stageB(0, 0, ldsB0); stageB(0, 1, ldsB0);
    stageA(0, 0, ldsA0); stageA(0, 1, ldsA0);
    asm volatile("s_waitcnt vmcnt(0)" ::: "memory");   // tile0 landed
    stageB(1, 0, ldsB1); stageB(1, 1, ldsB1);          // 4 copies in flight
    __builtin_amdgcn_s_barrier();
#pragma unroll
    for (int i = 0; i < 4; ++i)
        aq[i] = *(const bf16x8*)(ldsA0 + arow + i * 2048 + ck0);
#pragma unroll
    for (int n = 0; n < 4; ++n)
        bq0[n] = *(const bf16x8*)(ldsB0 + brow + n * 2048 + ck0);
    __builtin_amdgcn_sched_barrier(0);

#pragma unroll 2
    for (int t = 0; t < NKT; ++t) {
        char* As = (t & 1) ? ldsA1 : ldsA0;
        char* Bs = (t & 1) ? ldsB1 : ldsB0;
        char* An = (t & 1) ? ldsA0 : ldsA1;   // tile t+1 slots
        char* Bn = (t & 1) ? ldsB0 : ldsB1;

        // ---- P0: MFMA (m0-3, k0) -----------------------------------------
#pragma unroll
        for (int i = 0; i < 4; ++i)
            ar[i] = *(const bf16x8*)(As + arow + (4 + i) * 2048 + ck0);
        __builtin_amdgcn_sched_barrier(0);
        if (t + 1 < NKT) stageA(t + 1, 0, An);
        __builtin_amdgcn_s_barrier();
        asm volatile("s_waitcnt lgkmcnt(4)" ::: "memory");
        __builtin_amdgcn_sched_barrier(0);
        __builtin_amdgcn_s_setprio(1);
        MFMA16(0, aq, bq0);
        __builtin_amdgcn_s_setprio(0);
        __builtin_amdgcn_s_barrier();

        // ---- P1: MFMA (m4-7, k0) -----------------------------------------
#pragma unroll
        for (int i = 0; i < 4; ++i)
            aq[i] = *(const bf16x8*)(As + arow + i * 2048 + ck1);
#pragma unroll
        for (int n = 0; n < 4; ++n)
            bq1[n] = *(const bf16x8*)(Bs + brow + n * 2048 + ck1);
        __builtin_amdgcn_sched_barrier(0);
        if (t + 1 < NKT) stageA(t + 1, 1, An);
        __builtin_amdgcn_s_barrier();
        asm volatile("s_waitcnt lgkmcnt(8)" ::: "memory");
        __builtin_amdgcn_sched_barrier(0);
        __builtin_amdgcn_s_setprio(1);
        MFMA16(4, ar, bq0);
        __builtin_amdgcn_s_setprio(0);
        __builtin_amdgcn_s_barrier();

        // ---- P2: MFMA (m0-3, k1) -----------------------------------------
#pragma unroll
        for (int i = 0; i < 4; ++i)
            ar[i] = *(const bf16x8*)(As + arow + (4 + i) * 2048 + ck1);
        __builtin_amdgcn_sched_barrier(0);
        __builtin_amdgcn_s_barrier();
        asm volatile("s_waitcnt lgkmcnt(4)" ::: "memory");
        __builtin_amdgcn_sched_barrier(0);
        if (t + 2 < NKT) stageB(t + 2, 0, Bs);   // bq1 reads of B(t) drained
        __builtin_amdgcn_s_setprio(1);
        MFMA16(0, aq, bq1);
        __builtin_amdgcn_s_setprio(0);
        __builtin_amdgcn_s_barrier();

        // ---- P3: MFMA (m4-7, k1) -----------------------------------------
        if (t + 2 < NKT) {
            stageB(t + 2, 1, Bs);
            asm volatile("s_waitcnt vmcnt(4)" ::: "memory");  // A(t+1),B(t+1) in
        } else {
            asm volatile("s_waitcnt vmcnt(0)" ::: "memory");
        }
        if (t + 1 < NKT) {
#pragma unroll
            for (int i = 0; i < 4; ++i)
                aq[i] = *(const bf16x8*)(An + arow + i * 2048 + ck0);
#pragma unroll
            for (int n = 0; n < 4; ++n)
                bq0[n] = *(const bf16x8*)(Bn + brow + n * 2048 + ck0);
        }
        __builtin_amdgcn_sched_barrier(0);
        __builtin_amdgcn_s_barrier();
        if (t + 1 < NKT)
            asm volatile("s_waitcnt lgkmcnt(8)" ::: "memory");
        else
            asm volatile("s_waitcnt lgkmcnt(0)" ::: "memory");
        __builtin_amdgcn_sched_barrier(0);
        __builtin_amdgcn_s_setprio(1);
        MFMA16(4, ar, bq1);
        __builtin_amdgcn_s_setprio(0);
        __builtin_amdgcn_s_barrier();
    }

    // ---- epilogue: C/D layout col = lane&15, row = quad*4 + reg -----------
#pragma unroll
    for (int i = 0; i < 8; ++i) {
#pragma unroll
        for (int n = 0; n < 4; ++n) {
            const int col = bn + wn + n * 16 + nl;
#pragma unroll
            for (int r = 0; r < 4; ++r) {
                const int m = bm + wm + i * 16 + quad * 4 + r;
                const float vv = acc[i][n][r];
                if constexpr (__is_same(OutT, float))
                    C[(size_t)m * ldc + col] = vv;
                else
                    C[(size_t)m * ldc + col] = __float2bfloat16(vv);
            }
        }
    }
}

// ---------------------------------------------------------------------------
// WKV scan, chunk-parallel over T (linear recurrence decomposition, log2-max
// form).  S1: per-(channel,chunk) aggregates; S2: fold + emit gated outputs.
// kr interleaved [M, 2C]: k at col c, r(=v) at col C+c.  Output sy [M, C].
// ---------------------------------------------------------------------------
#define L2E 1.4426950408889634f

struct Blk { u16 k[8]; u16 v[8]; };

__device__ __forceinline__ void load8(const u16* kp, const u16* vp,
                                      int t, int S, Blk& B) {
#pragma unroll
    for (int j = 0; j < 8; ++j) {
        B.k[j] = kp[(size_t)(t + j) * S];
        B.v[j] = vp[(size_t)(t + j) * S];
    }
}

__device__ __forceinline__ float bf2f(u16 r) {
    return __uint_as_float(((unsigned)r) << 16);
}

// state-only update (S1 aggregates): d=(pp+w)-k in log2 domain
__device__ __forceinline__ void wkv_state_step(
    u16 kraw, u16 vraw, float w2, float& a, float& bb, float& pp2)
{
    const float kf = bf2f(kraw);
    const float vf = bf2f(vraw);
    const float k2 = kf * L2E;
    const float d   = pp2 + w2 - k2;
    const float m0  = fminf(d, 0.f);
    const float e1b = __builtin_amdgcn_exp2f(m0);
    const float e2b = __builtin_amdgcn_exp2f(m0 - d);
    a   = e1b * a  + e2b * vf;
    bb  = e1b * bb + e2b;
    pp2 = k2 + fmaxf(d, 0.f);
}

__device__ __forceinline__ void wkv_step(
    u16 kraw, u16 vraw, float u2, float w2,
    float& a, float& bb, float& pp2, __hip_bfloat16* op)
{
    const float kf = bf2f(kraw);
    const float vf = bf2f(vraw);
    const float k2 = kf * L2E;

    // output: y = (e1*a + e2*v)/(e1*bb + e2), divided through by e2 (q cancels)
    const float ww2 = u2 + k2;
    const float s   = __builtin_amdgcn_exp2f(fminf(pp2 - ww2, 60.f));
    const float num = s * a + vf;
    const float den = s * bb + 1.f;
    // gate: sigmoid(v) folded into a single reciprocal
    const float e   = __builtin_amdgcn_exp2f(-L2E * vf);
    const float res = num * __builtin_amdgcn_rcpf(den * (1.f + e));
    *op = __float2bfloat16(res);

    // state: d=(pp+w)-k (log2); e1b=2^min(d,0), e2b=2^(min(d,0)-d)
    const float d   = pp2 + w2 - k2;
    const float m0  = fminf(d, 0.f);
    const float e1b = __builtin_amdgcn_exp2f(m0);
    const float e2b = __builtin_amdgcn_exp2f(m0 - d);
    a   = e1b * a  + e2b * vf;
    bb  = e1b * bb + e2b;
    pp2 = k2 + fmaxf(d, 0.f);
}

// S1: per-(channel, chunk) aggregate.  gid2 = chunk*NCH + ch (coalesced agg
// layout [chunk][ch] for S2's fold loop).
__global__ __launch_bounds__(256) void wkv_agg_kernel(
    const __hip_bfloat16* __restrict__ kr,
    const float* __restrict__ td,
    float* __restrict__ aggA, float* __restrict__ aggB,
    float* __restrict__ aggP, int T, int C)
{
    const int gid2  = blockIdx.x * 256 + threadIdx.x;
    const int ch    = gid2 & (NCH - 1);
    const int chunk = gid2 >> 14;
    const int b = ch >> 10;
    const int c = ch & (C - 1);
    const int S = 2 * C;

    const float w2 = -__expf(td[c]) * L2E;

    const u16* kp = (const u16*)(kr + (size_t)b * T * S + c)
                    + (size_t)(chunk * CL) * S;
    const u16* vp = kp + C;

    float a = 0.f, bb = 0.f, pp2 = -1.4427e38f;

    Blk A, Bq;
    load8(kp, vp, 0, S, A);
    for (int tb = 0; tb < CL; tb += 16) {
        load8(kp, vp, tb + 8, S, Bq);
#pragma unroll
        for (int j = 0; j < 8; ++j)
            wkv_state_step(A.k[j], A.v[j], w2, a, bb, pp2);
        if (tb + 16 < CL) load8(kp, vp, tb + 16, S, A);
#pragma unroll
        for (int j = 0; j < 8; ++j)
            wkv_state_step(Bq.k[j], Bq.v[j], w2, a, bb, pp2);
    }
    aggA[gid2] = a;
    aggB[gid2] = bb;
    aggP[gid2] = pp2;
}

// S2: fold incoming state from preceding chunk aggregates, then emit outputs.
__global__ __launch_bounds__(256) void wkv_out_kernel(
    const __hip_bfloat16* __restrict__ kr,
    const float* __restrict__ tf, const float* __restrict__ td,
    const float* __restrict__ aggA, const float* __restrict__ aggB,
    const float* __restrict__ aggP,
    __hip_bfloat16* __restrict__ sy, int T, int C)
{
    const int gid2  = blockIdx.x * 256 + threadIdx.x;
    const int ch    = gid2 & (NCH - 1);
    const int chunk = gid2 >> 14;   // uniform per block (64 blocks/chunk)
    const int b = ch >> 10;
    const int c = ch & (C - 1);
    const int S = 2 * C;

    const float u2 = tf[c] * L2E;
    const float w2 = -__expf(td[c]) * L2E;

    // incoming state = fold of aggregates j < chunk, decayed (chunk-1-j)*CL
    float a = 0.f, bb = 0.f, pp2 = -1.4427e38f;
    for (int j = 0; j < chunk; ++j) {
        const float p  = aggP[j * NCH + ch]
                         + (float)((chunk - 1 - j) * CL) * w2;
        const float Aj = aggA[j * NCH + ch];
        const float Bj = aggB[j * NCH + ch];
        const float q  = fmaxf(pp2, p);
        const float e1 = __builtin_amdgcn_exp2f(pp2 - q);
        const float e2 = __builtin_amdgcn_exp2f(p - q);
        a   = e1 * a  + e2 * Aj;
        bb  = e1 * bb + e2 * Bj;
        pp2 = q;
    }

    const int t0 = chunk * CL;
    const u16* kp = (const u16*)(kr + (size_t)b * T * S + c) + (size_t)t0 * S;
    const u16* vp = kp + C;
    __hip_bfloat16* op = sy + (size_t)b * T * C + (size_t)t0 * C + c;

    Blk A, Bq;
    load8(kp, vp, 0, S, A);
    for (int tb = 0; tb < CL; tb += 16) {
        load8(kp, vp, tb + 8, S, Bq);
#pragma unroll
        for (int j = 0; j < 8; ++j)
            wkv_step(A.k[j], A.v[j], u2, w2, a, bb, pp2,
                     op + (size_t)(tb + j) * C);
        if (tb + 16 < CL) load8(kp, vp, tb + 16, S, A);
#pragma unroll
        for (int j = 0; j < 8; ++j)
            wkv_step(Bq.k[j], Bq.v[j], u2, w2, a, bb, pp2,
                     op + (size_t)(tb + 8 + j) * C);
    }
}

extern "C" void kernel_launch(void* const* d_in, const int* in_sizes, int n_in,
                              void* d_out, int out_size, void* d_ws, size_t ws_size,
                              hipStream_t stream) {
    const float* x  = (const float*)d_in[0];
    const float* Wk = (const float*)d_in[1];
    const float* Wr = (const float*)d_in[2];
    const float* Wo = (const float*)d_in[3];
    const float* td = (const float*)d_in[4];
    const float* tf = (const float*)d_in[5];
    float* out = (float*)d_out;

    const int B = 16, T = 1024, C = 1024;
    const int M = B * T;                       // 16384
    const int MC = M * C;                      // 16,777,216
    const int CC = C * C;                      // 1,048,576

    // ws layout (bf16): xb [MC] | Wkb [CC] | Wrb [CC] | Wob [CC]   (38 MiB)
    __hip_bfloat16* xb  = (__hip_bfloat16*)d_ws;
    __hip_bfloat16* Wkb = xb + (size_t)MC;
    __hip_bfloat16* Wrb = Wkb + (size_t)CC;
    __hip_bfloat16* Wob = Wrb + (size_t)CC;
    __hip_bfloat16* sy  = xb;                  // reuses xb slot (xb dead)

    // scan aggregates reuse Wkb/Wrb slots (dead after kr-GEMM)
    float* aggA = (float*)Wkb;
    float* aggB = aggA + (size_t)NCH * NC;     // 262,144 floats each
    float* aggP = (float*)Wrb;

    // d_out mid-pipeline: kr bf16 [M, 2C]
    __hip_bfloat16* kr = (__hip_bfloat16*)d_out;

    // 1) casts fp32 -> bf16
    cast_f32_bf16_kernel<<<MC / 1024, 256, 0, stream>>>(x,  xb,  MC);
    cast_f32_bf16_kernel<<<CC / 1024, 256, 0, stream>>>(Wk, Wkb, CC);
    cast_f32_bf16_kernel<<<CC / 1024, 256, 0, stream>>>(Wr, Wrb, CC);
    cast_f32_bf16_kernel<<<CC / 1024, 256, 0, stream>>>(Wo, Wob, CC);

    // 2) fused kr GEMM: kr[m, 0:C] = xb Wkb^T, kr[m, C:2C] = xb Wrb^T
    //    grid = (M/256) * (2C/256) = 64*8 = 512 (%8 == 0 for XCD swizzle)
    gemm256_kernel<__hip_bfloat16><<<dim3((M / 256) * (2 * C / 256)), 512, 0,
                                     stream>>>(xb, Wkb, Wrb, kr, 2 * C, C, 8);

    // 3a) scan pass 1: chunk aggregates (NCH*NC threads)
    wkv_agg_kernel<<<dim3(NCH * NC / 256), 256, 0, stream>>>(
        kr, td, aggA, aggB, aggP, T, C);

    // 3b) scan pass 2: fold + outputs -> sy (ws, xb slot)
    wkv_out_kernel<<<dim3(NCH * NC / 256), 256, 0, stream>>>(
        kr, tf, td, aggA, aggB, aggP, sy, T, C);

    // 4) out = sy Wob^T -> d_out as fp32 (overwrites kr; sy lives in ws)
    //    grid = 64*4 = 256 (%8 == 0)
    gemm256_kernel<float><<<dim3((M / 256) * (C / 256)), 512, 0, stream>>>(
        sy, Wob, Wob, out, C, C, 4);
}

// Round 4
// 257.385 us; speedup vs baseline: 1.3766x; 1.3766x over previous
//
#include <hip/hip_runtime.h>
#include <hip/hip_bf16.h>

// ---------------------------------------------------------------------------
// RWKV TimeMix:  k = x Wk^T ; r = x Wr^T ; v = r ; y = wkv(w,u,k,v)
//                out = (sigmoid(r) * y) Wo^T
// B=16, T=1024, C=1024.  All inputs and the output are FLOAT32.
//
// Pipeline: single fused fp32->bf16 cast kernel (x,Wk,Wr,Wo); fused kr-GEMM
// (N=2048, Wk|Wr split) and final GEMM via the 256x256 8-phase bf16 MFMA
// template (T1 XCD swizzle, T2 LDS XOR-swizzle, T3/T4 counted-vmcnt phases,
// T5 setprio); WKV scan chunk-parallel over T (16 chunks of 64), two passes.
//
// R3 note: the R2 GEMM (80 us, MfmaUtil 34.7%) is restored verbatim — the
// R3 fragment-pipelined variant spilled (VGPR 112->128, +29 MB scratch
// writes/dispatch) and regressed to 133 us.  This round cuts launch count
// 8 -> 5 (casts fused): measured ~10 us/launch fixed overhead.
//
// Memory plan:
//   ws:    [xb 32 MiB][Wkb 2][Wrb 2][Wob 2]  (38 MiB; sy reuses xb slot;
//          scan aggregates reuse Wkb/Wrb slots — dead after kr-GEMM)
//   d_out: 64 MiB fp32 — mid-pipeline holds kr bf16 [M, 2C]; finally
//          overwritten with fp32 out (gemm3 reads sy from ws).
// ---------------------------------------------------------------------------

typedef __attribute__((ext_vector_type(8))) short bf16x8;   // 8 bf16 = 4 VGPRs
typedef __attribute__((ext_vector_type(4))) float f32x4;    // MFMA C/D
typedef unsigned short u16;

#define GK   1024          // K of both GEMMs (= C)
#define NKT  16            // GK / 64 K-tiles
#define ROWB 2048l         // bytes per B^T/A row = GK * 2

#define NCH  16384         // B * C channels
#define NC   16            // scan chunks over T
#define CL   64            // chunk length (T / NC)

__device__ __forceinline__ void async_copy16(const void* g, void* l) {
    __builtin_amdgcn_global_load_lds(
        (const __attribute__((address_space(1))) void*)g,
        (__attribute__((address_space(3))) void*)l,
        16 /*bytes*/, 0 /*offset*/, 0 /*aux*/);
}

// ---- fused fp32 -> bf16 cast for all 4 tensors, 4 elems/thread ------------
// Block ranges: [0,16384) -> x (16M elems), then 1024 blocks each for
// Wk, Wr, Wo (1M elems).  All sizes exact multiples of 1024 elems/block.
__global__ __launch_bounds__(256) void cast_all_kernel(
    const float* __restrict__ x,  const float* __restrict__ wk,
    const float* __restrict__ wr, const float* __restrict__ wo,
    __hip_bfloat16* __restrict__ xb,  __hip_bfloat16* __restrict__ wkb,
    __hip_bfloat16* __restrict__ wrb, __hip_bfloat16* __restrict__ wob)
{
    const int bid = blockIdx.x;
    const float* src;
    __hip_bfloat16* dst;
    int blk;
    if (bid < 16384)      { src = x;  dst = xb;  blk = bid; }
    else if (bid < 17408) { src = wk; dst = wkb; blk = bid - 16384; }
    else if (bid < 18432) { src = wr; dst = wrb; blk = bid - 17408; }
    else                  { src = wo; dst = wob; blk = bid - 18432; }

    const int i = blk * 1024 + threadIdx.x * 4;
    const f32x4 v = *(const f32x4*)(src + i);
    __hip_bfloat16 o[4];
    o[0] = __float2bfloat16(v[0]);
    o[1] = __float2bfloat16(v[1]);
    o[2] = __float2bfloat16(v[2]);
    o[3] = __float2bfloat16(v[3]);
    *(__attribute__((ext_vector_type(4))) short*)(dst + i) =
        *(__attribute__((ext_vector_type(4))) short*)o;
}

// ---------------------------------------------------------------------------
// 256x256 tile, BK=64, 8 waves (2M x 4N), 512 threads, 128 KiB LDS dbuf.
// C[m, bn+n] = sum_k A[m,k] * Bt[n,k];  Bt source = B0 for n < nsplit else B1.
//
// LDS layout per slot (two slots, 64 KiB each):
//   A tile [256 rows][128 B]  then  B tile [256 rows][128 B]
// Swizzle: phys_col = log_col ^ ((row & 7) << 4)  (involution; staging writes
// linear LDS from the inverse-swizzled GLOBAL address, reads apply the XOR).
//
// Per K-tile: 4 phases; phase q = { ds_read A-frags i=2q,2q+1 (B-frags at
// q==0) | stage one half-tile | barrier | lgkmcnt(0) | setprio(1) 16 MFMA
// setprio(0) | barrier }.  Staging schedule (1.5 tiles ahead, write-safe):
//   q0: A-half0(t+1)  q1: A-half1(t+1)  q2: B-half0(t+2)  q3: B-half1(t+2)
// vmcnt(4) once per tile at q3 (2 half-tiles in flight), vmcnt(0) only at
// the pipeline tail.
// ---------------------------------------------------------------------------

#define PHASE(I0, STAGE_STMT) do {                                            \
    bf16x8 a00 = *(const bf16x8*)(As + arow + (I0) * 2048 + ck0);             \
    bf16x8 a01 = *(const bf16x8*)(As + arow + (I0) * 2048 + ck1);             \
    bf16x8 a10 = *(const bf16x8*)(As + arow + (I0 + 1) * 2048 + ck0);         \
    bf16x8 a11 = *(const bf16x8*)(As + arow + (I0 + 1) * 2048 + ck1);         \
    STAGE_STMT;                                                               \
    __builtin_amdgcn_s_barrier();                                             \
    asm volatile("s_waitcnt lgkmcnt(0)" ::: "memory");                        \
    __builtin_amdgcn_sched_barrier(0);                                        \
    __builtin_amdgcn_s_setprio(1);                                            \
    _Pragma("unroll")                                                         \
    for (int n = 0; n < 4; ++n) {                                             \
        acc[I0][n]     = __builtin_amdgcn_mfma_f32_16x16x32_bf16(             \
                             a00, bf[n][0], acc[I0][n], 0, 0, 0);             \
        acc[I0][n]     = __builtin_amdgcn_mfma_f32_16x16x32_bf16(             \
                             a01, bf[n][1], acc[I0][n], 0, 0, 0);             \
        acc[I0 + 1][n] = __builtin_amdgcn_mfma_f32_16x16x32_bf16(             \
                             a10, bf[n][0], acc[I0 + 1][n], 0, 0, 0);         \
        acc[I0 + 1][n] = __builtin_amdgcn_mfma_f32_16x16x32_bf16(             \
                             a11, bf[n][1], acc[I0 + 1][n], 0, 0, 0);         \
    }                                                                         \
    __builtin_amdgcn_s_setprio(0);                                            \
    __builtin_amdgcn_s_barrier();                                            \
} while (0)

template <typename OutT>
__global__ __launch_bounds__(512, 2) void gemm256_kernel(
    const __hip_bfloat16* __restrict__ A,
    const __hip_bfloat16* __restrict__ B0,
    const __hip_bfloat16* __restrict__ B1,
    OutT* __restrict__ C,
    int ldc, int nsplit, int ntn)
{
    __shared__ __align__(16) char lds[131072];

    const int tid = threadIdx.x;

    // XCD-aware bijective swizzle (gridDim.x % 8 == 0 for both launches)
    const int nwg = gridDim.x;
    const int cpx = nwg >> 3;
    const int wg  = blockIdx.x;
    const int swz = (wg & 7) * cpx + (wg >> 3);
    const int bm  = (swz / ntn) * 256;
    const int bn  = (swz % ntn) * 256;

    const __hip_bfloat16* Bsrc;
    int bnl;
    if (bn < nsplit) { Bsrc = B0; bnl = bn; }
    else             { Bsrc = B1; bnl = bn - nsplit; }

    const int lane = tid & 63;
    const int wave = tid >> 6;
    const int nl   = lane & 15;
    const int quad = lane >> 4;
    const int wm   = (wave >> 2) * 128;   // 2 m-waves
    const int wn   = (wave & 3) * 64;     // 4 n-waves

    // ---- staging addresses: linear LDS dest, inverse-swizzled global src --
    const int r0 = tid >> 3;                          // row in half-tile 0..63
    const int cs = ((tid & 7) ^ (r0 & 7)) << 4;       // swizzled col byte
    const int od = tid * 16;                          // linear dest (o1=+8192)
    const char* Ag = (const char*)A    + (size_t)(bm  + r0) * ROWB + cs;
    const char* Bg = (const char*)Bsrc + (size_t)(bnl + r0) * ROWB + cs;

    char* ldsA0 = lds;
    char* ldsB0 = lds + 32768;
    char* ldsA1 = lds + 65536;
    char* ldsB1 = lds + 98304;

    auto stageA = [&](int kt, int h, char* dstA) {
        const char* g = Ag + (size_t)h * 128 * ROWB + (size_t)kt * 128;
        async_copy16(g,             dstA + h * 16384 + od);
        async_copy16(g + 64 * ROWB, dstA + h * 16384 + od + 8192);
    };
    auto stageB = [&](int kt, int h, char* dstB) {
        const char* g = Bg + (size_t)h * 128 * ROWB + (size_t)kt * 128;
        async_copy16(g,             dstB + h * 16384 + od);
        async_copy16(g + 64 * ROWB, dstB + h * 16384 + od + 8192);
    };

    // ---- fragment read offsets (swizzled) ---------------------------------
    const int rw   = nl & 7;
    const int ck0  = (quad ^ rw) << 4;         // kk=0: byte col in 128B row
    const int ck1  = ((4 + quad) ^ rw) << 4;   // kk=1
    const int arow = (wm + nl) * 128;          // byte row offset in A tile
    const int brow = (wn + nl) * 128;          // byte row offset in B tile

    f32x4 acc[8][4] = {};

    // ---- prologue: tile0 (B0,B1,A0,A1) + tile1 (B0,B1) --------------------
    stageB(0, 0, ldsB0); stageB(0, 1, ldsB0);
    stageA(0, 0, ldsA0); stageA(0, 1, ldsA0);
    stageB(1, 0, ldsB1); stageB(1, 1, ldsB1);
    asm volatile("s_waitcnt vmcnt(4)" ::: "memory");   // tile0 landed
    __builtin_amdgcn_s_barrier();

#pragma unroll 2
    for (int t = 0; t < NKT; ++t) {
        char* As = (t & 1) ? ldsA1 : ldsA0;
        char* Bs = (t & 1) ? ldsB1 : ldsB0;
        char* Ao = (t & 1) ? ldsA0 : ldsA1;   // A dest for tile t+1
        // B dest for tile t+2 is the CURRENT slot's B (consumed in phase 0)

        bf16x8 bf[4][2];
#pragma unroll
        for (int n = 0; n < 4; ++n) {
            bf[n][0] = *(const bf16x8*)(Bs + brow + n * 2048 + ck0);
            bf[n][1] = *(const bf16x8*)(Bs + brow + n * 2048 + ck1);
        }

        PHASE(0, if (t + 1 < NKT) stageA(t + 1, 0, Ao));
        PHASE(2, if (t + 1 < NKT) stageA(t + 1, 1, Ao));
        PHASE(4, if (t + 2 < NKT) stageB(t + 2, 0, Bs));
        PHASE(6, {
            if (t + 2 < NKT) {
                stageB(t + 2, 1, Bs);
                asm volatile("s_waitcnt vmcnt(4)" ::: "memory");
            } else {
                asm volatile("s_waitcnt vmcnt(0)" ::: "memory");
            }
        });
    }

    // ---- epilogue: C/D layout col = lane&15, row = quad*4 + reg -----------
#pragma unroll
    for (int i = 0; i < 8; ++i) {
#pragma unroll
        for (int n = 0; n < 4; ++n) {
            const int col = bn + wn + n * 16 + nl;
#pragma unroll
            for (int r = 0; r < 4; ++r) {
                const int m = bm + wm + i * 16 + quad * 4 + r;
                const float vv = acc[i][n][r];
                if constexpr (__is_same(OutT, float))
                    C[(size_t)m * ldc + col] = vv;
                else
                    C[(size_t)m * ldc + col] = __float2bfloat16(vv);
            }
        }
    }
}

// ---------------------------------------------------------------------------
// WKV scan, chunk-parallel over T (linear recurrence decomposition, log2-max
// form).  S1: per-(channel,chunk) aggregates; S2: fold + emit gated outputs.
// kr interleaved [M, 2C]: k at col c, r(=v) at col C+c.  Output sy [M, C].
// ---------------------------------------------------------------------------
#define L2E 1.4426950408889634f

struct Blk { u16 k[8]; u16 v[8]; };

__device__ __forceinline__ void load8(const u16* kp, const u16* vp,
                                      int t, int S, Blk& B) {
#pragma unroll
    for (int j = 0; j < 8; ++j) {
        B.k[j] = kp[(size_t)(t + j) * S];
        B.v[j] = vp[(size_t)(t + j) * S];
    }
}

__device__ __forceinline__ float bf2f(u16 r) {
    return __uint_as_float(((unsigned)r) << 16);
}

// state-only update (S1 aggregates): d=(pp+w)-k in log2 domain
__device__ __forceinline__ void wkv_state_step(
    u16 kraw, u16 vraw, float w2, float& a, float& bb, float& pp2)
{
    const float kf = bf2f(kraw);
    const float vf = bf2f(vraw);
    const float k2 = kf * L2E;
    const float d   = pp2 + w2 - k2;
    const float m0  = fminf(d, 0.f);
    const float e1b = __builtin_amdgcn_exp2f(m0);
    const float e2b = __builtin_amdgcn_exp2f(m0 - d);
    a   = e1b * a  + e2b * vf;
    bb  = e1b * bb + e2b;
    pp2 = k2 + fmaxf(d, 0.f);
}

__device__ __forceinline__ void wkv_step(
    u16 kraw, u16 vraw, float u2, float w2,
    float& a, float& bb, float& pp2, __hip_bfloat16* op)
{
    const float kf = bf2f(kraw);
    const float vf = bf2f(vraw);
    const float k2 = kf * L2E;

    // output: y = (e1*a + e2*v)/(e1*bb + e2), divided through by e2 (q cancels)
    const float ww2 = u2 + k2;
    const float s   = __builtin_amdgcn_exp2f(fminf(pp2 - ww2, 60.f));
    const float num = s * a + vf;
    const float den = s * bb + 1.f;
    // gate: sigmoid(v) folded into a single reciprocal
    const float e   = __builtin_amdgcn_exp2f(-L2E * vf);
    const float res = num * __builtin_amdgcn_rcpf(den * (1.f + e));
    *op = __float2bfloat16(res);

    // state: d=(pp+w)-k (log2); e1b=2^min(d,0), e2b=2^(min(d,0)-d)
    const float d   = pp2 + w2 - k2;
    const float m0  = fminf(d, 0.f);
    const float e1b = __builtin_amdgcn_exp2f(m0);
    const float e2b = __builtin_amdgcn_exp2f(m0 - d);
    a   = e1b * a  + e2b * vf;
    bb  = e1b * bb + e2b;
    pp2 = k2 + fmaxf(d, 0.f);
}

// S1: per-(channel, chunk) aggregate.  gid2 = chunk*NCH + ch (coalesced agg
// layout [chunk][ch] for S2's fold loop).
__global__ __launch_bounds__(256) void wkv_agg_kernel(
    const __hip_bfloat16* __restrict__ kr,
    const float* __restrict__ td,
    float* __restrict__ aggA, float* __restrict__ aggB,
    float* __restrict__ aggP, int T, int C)
{
    const int gid2  = blockIdx.x * 256 + threadIdx.x;
    const int ch    = gid2 & (NCH - 1);
    const int chunk = gid2 >> 14;
    const int b = ch >> 10;
    const int c = ch & (C - 1);
    const int S = 2 * C;

    const float w2 = -__expf(td[c]) * L2E;

    const u16* kp = (const u16*)(kr + (size_t)b * T * S + c)
                    + (size_t)(chunk * CL) * S;
    const u16* vp = kp + C;

    float a = 0.f, bb = 0.f, pp2 = -1.4427e38f;

    Blk A, Bq;
    load8(kp, vp, 0, S, A);
    for (int tb = 0; tb < CL; tb += 16) {
        load8(kp, vp, tb + 8, S, Bq);
#pragma unroll
        for (int j = 0; j < 8; ++j)
            wkv_state_step(A.k[j], A.v[j], w2, a, bb, pp2);
        if (tb + 16 < CL) load8(kp, vp, tb + 16, S, A);
#pragma unroll
        for (int j = 0; j < 8; ++j)
            wkv_state_step(Bq.k[j], Bq.v[j], w2, a, bb, pp2);
    }
    aggA[gid2] = a;
    aggB[gid2] = bb;
    aggP[gid2] = pp2;
}

// S2: fold incoming state from preceding chunk aggregates, then emit outputs.
__global__ __launch_bounds__(256) void wkv_out_kernel(
    const __hip_bfloat16* __restrict__ kr,
    const float* __restrict__ tf, const float* __restrict__ td,
    const float* __restrict__ aggA, const float* __restrict__ aggB,
    const float* __restrict__ aggP,
    __hip_bfloat16* __restrict__ sy, int T, int C)
{
    const int gid2  = blockIdx.x * 256 + threadIdx.x;
    const int ch    = gid2 & (NCH - 1);
    const int chunk = gid2 >> 14;   // uniform per block (64 blocks/chunk)
    const int b = ch >> 10;
    const int c = ch & (C - 1);
    const int S = 2 * C;

    const float u2 = tf[c] * L2E;
    const float w2 = -__expf(td[c]) * L2E;

    // incoming state = fold of aggregates j < chunk, decayed (chunk-1-j)*CL
    float a = 0.f, bb = 0.f, pp2 = -1.4427e38f;
    for (int j = 0; j < chunk; ++j) {
        const float p  = aggP[j * NCH + ch]
                         + (float)((chunk - 1 - j) * CL) * w2;
        const float Aj = aggA[j * NCH + ch];
        const float Bj = aggB[j * NCH + ch];
        const float q  = fmaxf(pp2, p);
        const float e1 = __builtin_amdgcn_exp2f(pp2 - q);
        const float e2 = __builtin_amdgcn_exp2f(p - q);
        a   = e1 * a  + e2 * Aj;
        bb  = e1 * bb + e2 * Bj;
        pp2 = q;
    }

    const int t0 = chunk * CL;
    const u16* kp = (const u16*)(kr + (size_t)b * T * S + c) + (size_t)t0 * S;
    const u16* vp = kp + C;
    __hip_bfloat16* op = sy + (size_t)b * T * C + (size_t)t0 * C + c;

    Blk A, Bq;
    load8(kp, vp, 0, S, A);
    for (int tb = 0; tb < CL; tb += 16) {
        load8(kp, vp, tb + 8, S, Bq);
#pragma unroll
        for (int j = 0; j < 8; ++j)
            wkv_step(A.k[j], A.v[j], u2, w2, a, bb, pp2,
                     op + (size_t)(tb + j) * C);
        if (tb + 16 < CL) load8(kp, vp, tb + 16, S, A);
#pragma unroll
        for (int j = 0; j < 8; ++j)
            wkv_step(Bq.k[j], Bq.v[j], u2, w2, a, bb, pp2,
                     op + (size_t)(tb + 8 + j) * C);
    }
}

extern "C" void kernel_launch(void* const* d_in, const int* in_sizes, int n_in,
                              void* d_out, int out_size, void* d_ws, size_t ws_size,
                              hipStream_t stream) {
    const float* x  = (const float*)d_in[0];
    const float* Wk = (const float*)d_in[1];
    const float* Wr = (const float*)d_in[2];
    const float* Wo = (const float*)d_in[3];
    const float* td = (const float*)d_in[4];
    const float* tf = (const float*)d_in[5];
    float* out = (float*)d_out;

    const int B = 16, T = 1024, C = 1024;
    const int M = B * T;                       // 16384
    const int MC = M * C;                      // 16,777,216
    const int CC = C * C;                      // 1,048,576

    // ws layout (bf16): xb [MC] | Wkb [CC] | Wrb [CC] | Wob [CC]   (38 MiB)
    __hip_bfloat16* xb  = (__hip_bfloat16*)d_ws;
    __hip_bfloat16* Wkb = xb + (size_t)MC;
    __hip_bfloat16* Wrb = Wkb + (size_t)CC;
    __hip_bfloat16* Wob = Wrb + (size_t)CC;
    __hip_bfloat16* sy  = xb;                  // reuses xb slot (xb dead)

    // scan aggregates reuse Wkb/Wrb slots (dead after kr-GEMM)
    float* aggA = (float*)Wkb;
    float* aggB = aggA + (size_t)NCH * NC;     // 262,144 floats each
    float* aggP = (float*)Wrb;

    // d_out mid-pipeline: kr bf16 [M, 2C]
    __hip_bfloat16* kr = (__hip_bfloat16*)d_out;

    // 1) fused casts fp32 -> bf16 (one launch: x | Wk | Wr | Wo)
    cast_all_kernel<<<dim3(16384 + 3 * 1024), 256, 0, stream>>>(
        x, Wk, Wr, Wo, xb, Wkb, Wrb, Wob);

    // 2) fused kr GEMM: kr[m, 0:C] = xb Wkb^T, kr[m, C:2C] = xb Wrb^T
    //    grid = (M/256) * (2C/256) = 64*8 = 512 (%8 == 0 for XCD swizzle)
    gemm256_kernel<__hip_bfloat16><<<dim3((M / 256) * (2 * C / 256)), 512, 0,
                                     stream>>>(xb, Wkb, Wrb, kr, 2 * C, C, 8);

    // 3a) scan pass 1: chunk aggregates (NCH*NC threads)
    wkv_agg_kernel<<<dim3(NCH * NC / 256), 256, 0, stream>>>(
        kr, td, aggA, aggB, aggP, T, C);

    // 3b) scan pass 2: fold + outputs -> sy (ws, xb slot)
    wkv_out_kernel<<<dim3(NCH * NC / 256), 256, 0, stream>>>(
        kr, tf, td, aggA, aggB, aggP, sy, T, C);

    // 4) out = sy Wob^T -> d_out as fp32 (overwrites kr; sy lives in ws)
    //    grid = 64*4 = 256 (%8 == 0)
    gemm256_kernel<float><<<dim3((M / 256) * (C / 256)), 512, 0, stream>>>(
        sy, Wob, Wob, out, C, C, 4);
}